// Round 1
// baseline (2007.650 us; speedup 1.0000x reference)
//
#include <hip/hip_runtime.h>
#include <stdint.h>

typedef unsigned long long u64;
typedef unsigned int u32;

// ---------------------------------------------------------------------------
// Problem constants (from reference): 17 features/row, beta = col 9,
// cluster coords = cols 14..16, T_B = 0.85, T_D^2 = 0.09.
// Only points with beta >= T_B can ever be condensation picks, and the
// assignment state of non-candidates never affects outputs -> operate on the
// compacted candidate set only (~15% of rows).
// ---------------------------------------------------------------------------

__global__ void init_kernel(int* candCount, int* condCount, int nseg) {
    int t = threadIdx.x;
    if (t < nseg) { candCount[t] = 0; condCount[t] = 0; }
}

__global__ void filter_kernel(const float* __restrict__ x, int N, int S,
                              float4* __restrict__ candA, int* __restrict__ candIdx,
                              int* __restrict__ candCount, int CAP) {
    int i = blockIdx.x * blockDim.x + threadIdx.x;
    int stride = gridDim.x * blockDim.x;
    for (; i < N; i += stride) {
        float beta = x[(size_t)i * 17 + 9];
        if (beta >= 0.85f) {
            int s = i / S;
            int pos = atomicAdd(&candCount[s], 1);
            if (pos < CAP) {
                float cx = x[(size_t)i * 17 + 14];
                float cy = x[(size_t)i * 17 + 15];
                float cz = x[(size_t)i * 17 + 16];
                candA[(size_t)s * CAP + pos] = make_float4(cx, cy, cz, beta);
                candIdx[(size_t)s * CAP + pos] = i;
            }
        }
    }
}

// One block (1024 threads) per segment. Each pass: drop entries within T_D of
// the current center, compact survivors into the other buffer, and compute the
// max-(beta, lowest idx) survivor = next pick. Pass 0 uses a far-away fake
// center so it is a pure copy+argmax.
__launch_bounds__(1024)
__global__ void greedy_kernel(float4* __restrict__ A, int* __restrict__ iA,
                              float4* __restrict__ Bb, int* __restrict__ iB,
                              const int* __restrict__ candCount, int CAP,
                              int* __restrict__ condList, int* __restrict__ condCount,
                              int CCAP) {
    const int s = blockIdx.x;
    const int tid = threadIdx.x;
    const int lane = tid & 63;
    const int wid = tid >> 6;

    __shared__ u64 wkey[16];
    __shared__ float wcx[16], wcy[16], wcz[16];
    __shared__ int s_newN;
    __shared__ float s_ctr[3];
    __shared__ u64 s_bestkey;

    float4* cur = A + (size_t)s * CAP;
    int*    icur = iA + (size_t)s * CAP;
    float4* nxt = Bb + (size_t)s * CAP;
    int*    inxt = iB + (size_t)s * CAP;
    int n = candCount[s];
    if (n > CAP) n = CAP;
    int* clist = condList + (size_t)s * CCAP;

    float ctrx = 1e30f, ctry = 1e30f, ctrz = 1e30f;
    int cnt = 0;

    while (true) {
        if (tid == 0) s_newN = 0;
        __syncthreads();

        u64 bkey = 0; float bcx = 0.f, bcy = 0.f, bcz = 0.f;
        for (int j = tid; j < n; j += 1024) {
            float4 c = cur[j];
            int gi = icur[j];
            // match numpy/jax f32 semantics exactly: no FMA contraction,
            // ((dx^2 + dy^2) + dz^2) < f32(0.09)
            float dx = __fsub_rn(c.x, ctrx);
            float dy = __fsub_rn(c.y, ctry);
            float dz = __fsub_rn(c.z, ctrz);
            float dsq = __fadd_rn(__fadd_rn(__fmul_rn(dx, dx), __fmul_rn(dy, dy)),
                                  __fmul_rn(dz, dz));
            bool survive = !(dsq < 0.09f);
            u64 smask = __ballot(survive);
            if (survive) {
                u32 bb = __float_as_uint(c.w);  // beta in [0.85,1): bits monotone
                u64 key = ((u64)bb << 32) | (u64)(0xFFFFFFFFu - (u32)gi); // ties -> lowest idx
                if (key > bkey) { bkey = key; bcx = c.x; bcy = c.y; bcz = c.z; }
                int leader = __ffsll((unsigned long long)smask) - 1;
                int base = 0;
                if (lane == leader) base = atomicAdd(&s_newN, __popcll(smask));
                base = __shfl(base, leader);
                int off = __popcll(smask & ((1ull << lane) - 1ull));
                nxt[base + off] = c;
                inxt[base + off] = gi;
            }
        }

        // wave-level max reduce carrying the winner's coords
        for (int off = 32; off > 0; off >>= 1) {
            u64 ok = __shfl_down(bkey, off);
            float ox = __shfl_down(bcx, off);
            float oy = __shfl_down(bcy, off);
            float oz = __shfl_down(bcz, off);
            if (ok > bkey) { bkey = ok; bcx = ox; bcy = oy; bcz = oz; }
        }
        if (lane == 0) { wkey[wid] = bkey; wcx[wid] = bcx; wcy[wid] = bcy; wcz[wid] = bcz; }
        __syncthreads();
        if (wid == 0) {
            u64 k2 = (lane < 16) ? wkey[lane] : 0;
            float x2 = (lane < 16) ? wcx[lane] : 0.f;
            float y2 = (lane < 16) ? wcy[lane] : 0.f;
            float z2 = (lane < 16) ? wcz[lane] : 0.f;
            for (int off = 8; off > 0; off >>= 1) {
                u64 ok = __shfl_down(k2, off);
                float ox = __shfl_down(x2, off);
                float oy = __shfl_down(y2, off);
                float oz = __shfl_down(z2, off);
                if (ok > k2) { k2 = ok; x2 = ox; y2 = oy; z2 = oz; }
            }
            if (lane == 0) { s_bestkey = k2; s_ctr[0] = x2; s_ctr[1] = y2; s_ctr[2] = z2; }
        }
        __syncthreads();

        int newN = s_newN;
        if (newN == 0 || s_bestkey == 0) break;

        if (tid == 0 && cnt < CCAP)
            clist[cnt] = (int)(0xFFFFFFFFu - (u32)(s_bestkey & 0xFFFFFFFFull));
        cnt++;
        ctrx = s_ctr[0]; ctry = s_ctr[1]; ctrz = s_ctr[2];

        float4* t4 = cur; cur = nxt; nxt = t4;
        int* ti = icur; icur = inxt; inxt = ti;
        n = newN;
        __syncthreads();  // writers of nxt done before anyone re-reads as cur
    }
    if (tid == 0) condCount[s] = cnt;
}

// Rank-sort each segment's pick list ascending (lists are tiny, ~40 entries),
// place into global sorted order (segment-major = globally ascending), and
// write ncond (cumulative counts) as float32.
__global__ void finalize_kernel(const int* __restrict__ condList,
                                const int* __restrict__ condCount, int CCAP,
                                int* __restrict__ sorted, int* __restrict__ prefix,
                                float* __restrict__ ncond_out, int nseg, int rows) {
    __shared__ int lst[2048];
    __shared__ int pfx[9];
    int tid = threadIdx.x;
    if (tid == 0) {
        int acc = 0; pfx[0] = 0;
        for (int s2 = 0; s2 < nseg; s2++) { acc += condCount[s2]; pfx[s2 + 1] = acc; }
    }
    __syncthreads();
    if (tid <= nseg) { prefix[tid] = pfx[tid]; ncond_out[tid] = (float)pfx[tid]; }
    for (int s2 = 0; s2 < nseg; s2++) {
        int ns = condCount[s2]; if (ns > CCAP) ns = CCAP;
        for (int i = tid; i < ns; i += blockDim.x) lst[i] = condList[(size_t)s2 * CCAP + i];
        __syncthreads();
        for (int i = tid; i < ns; i += blockDim.x) {
            int v = lst[i]; int rank = 0;
            for (int j = 0; j < ns; j++) rank += (lst[j] < v);
            int pos = pfx[s2] + rank;
            if (pos < rows) sorted[pos] = v;
        }
        __syncthreads();
    }
}

__global__ void emit_kernel(const float* __restrict__ x, const int* __restrict__ sorted,
                            const int* __restrict__ prefix, float* __restrict__ out,
                            int rows, int nseg) {
    int e = blockIdx.x * blockDim.x + threadIdx.x;
    if (e >= rows * 17) return;
    int total = prefix[nseg];
    int j = e / 17, k = e - j * 17;
    float v = 0.f;
    if (j < total) v = x[(size_t)sorted[j] * 17 + k];
    out[e] = v;
}

extern "C" void kernel_launch(void* const* d_in, const int* in_sizes, int n_in,
                              void* d_out, int out_size, void* d_ws, size_t ws_size,
                              hipStream_t stream) {
    const float* x = (const float*)d_in[0];
    const int nseg = in_sizes[1] - 1;          // 4
    const int N = in_sizes[0] / 17;            // 1,000,000
    const int S = N / nseg;                    // 250,000
    const int rows = (out_size - (nseg + 1)) / 17;  // 1024 (MAX_COND)
    const int CCAP = 2048;

    // workspace layout: [A float4][B float4][iA][iB][condList][condCount][candCount][sorted][prefix]
    char* w = (char*)d_ws;
    size_t fixedBytes = (size_t)nseg * CCAP * 4 + (size_t)nseg * 4 * 2 +
                        (size_t)rows * 4 + (size_t)(nseg + 1) * 4 + 4096;
    size_t perCand = (size_t)nseg * 2 * (16 + 4);
    size_t avail = (ws_size > fixedBytes) ? (ws_size - fixedBytes) : 0;
    int CAP = (int)(avail / perCand);
    if (CAP > 65536) CAP = 65536;   // ~1.75x the expected 37.5k candidates/segment
    if (CAP < 1) CAP = 1;

    float4* A  = (float4*)w;
    float4* Bb = A + (size_t)nseg * CAP;
    int* iA = (int*)(Bb + (size_t)nseg * CAP);
    int* iB = iA + (size_t)nseg * CAP;
    int* condList  = iB + (size_t)nseg * CAP;
    int* condCount = condList + (size_t)nseg * CCAP;
    int* candCount = condCount + nseg;
    int* sorted    = candCount + nseg;
    int* prefix    = sorted + rows;
    float* out = (float*)d_out;

    init_kernel<<<1, 64, 0, stream>>>(candCount, condCount, nseg);
    filter_kernel<<<2048, 256, 0, stream>>>(x, N, S, A, iA, candCount, CAP);
    greedy_kernel<<<nseg, 1024, 0, stream>>>(A, iA, Bb, iB, candCount, CAP,
                                             condList, condCount, CCAP);
    finalize_kernel<<<1, 256, 0, stream>>>(condList, condCount, CCAP, sorted, prefix,
                                           out + (size_t)rows * 17, nseg, rows);
    emit_kernel<<<(rows * 17 + 255) / 256, 256, 0, stream>>>(x, sorted, prefix, out,
                                                             rows, nseg);
}

// Round 2
// 324.122 us; speedup vs baseline: 6.1941x; 6.1941x over previous
//
#include <hip/hip_runtime.h>
#include <stdint.h>

typedef unsigned long long u64;
typedef unsigned int u32;

// ---------------------------------------------------------------------------
// Problem constants (from reference): 17 features/row, beta = col 9,
// cluster coords = cols 14..16, T_B = 0.85, T_D^2 = 0.09.
// Only points with beta >= T_B can ever be condensation picks, and the
// assignment state of non-candidates never affects outputs -> operate on the
// compacted candidate set only (~15% of rows).
//
// R1: replaced the 4-global-counter atomic compaction (150k contended atomics
// = 1.7 ms at ~11ns each) with count -> scan -> scatter (zero global atomics).
// ---------------------------------------------------------------------------

// Phase 1: block b owns rows [s*S + c*chunk, min(+chunk, segment end));
// count candidates, no atomics.
__global__ void count_kernel(const float* __restrict__ x, int S, int chunk, int bps,
                             int* __restrict__ blockCount) {
    __shared__ int cnts[4];
    int b = blockIdx.x;
    int s = b / bps, c = b % bps;
    int start = s * S + c * chunk;
    int end = min(start + chunk, s * S + S);
    int tid = threadIdx.x, lane = tid & 63, wid = tid >> 6;
    int cnt = 0;
    for (int i = start + tid; i < end; i += blockDim.x)
        cnt += (x[(size_t)i * 17 + 9] >= 0.85f) ? 1 : 0;
    for (int off = 32; off > 0; off >>= 1) cnt += __shfl_down(cnt, off);
    if (lane == 0) cnts[wid] = cnt;
    __syncthreads();
    if (tid == 0) blockCount[b] = cnts[0] + cnts[1] + cnts[2] + cnts[3];
}

// Phase 2: exclusive scan of the (segment-major) block counts -> per-block
// base; segment totals fall out at the segment-boundary positions.
__global__ void scan_kernel(const int* __restrict__ blockCount, int nBlocks,
                            int* __restrict__ blockBase, int* __restrict__ candCount,
                            int nseg, int bps) {
    __shared__ int wsum[16];
    __shared__ int segIncl[8];
    int tid = threadIdx.x;
    int lane = tid & 63, wid = tid >> 6;
    int v = (tid < nBlocks) ? blockCount[tid] : 0;
    int incl = v;
    for (int off = 1; off < 64; off <<= 1) {
        int o = __shfl_up(incl, off);
        if (lane >= off) incl += o;
    }
    if (lane == 63) wsum[wid] = incl;
    __syncthreads();
    if (wid == 0) {
        int sacc = (lane < 16) ? wsum[lane] : 0;
        for (int off = 1; off < 16; off <<= 1) {
            int o = __shfl_up(sacc, off);
            if (lane >= off) sacc += o;
        }
        if (lane < 16) wsum[lane] = sacc;
    }
    __syncthreads();
    int waveBase = (wid > 0) ? wsum[wid - 1] : 0;
    int inclusive = incl + waveBase;
    if (tid < nBlocks) blockBase[tid] = inclusive - v;
    if (tid < nBlocks && (tid % bps == bps - 1)) segIncl[tid / bps] = inclusive;
    __syncthreads();
    if (tid < nseg) candCount[tid] = segIncl[tid] - (tid ? segIncl[tid - 1] : 0);
}

// Phase 3: re-scan, place candidates at segment-relative base + LDS-local
// offset. Only block-local LDS atomics (uncontended).
__global__ void scatter_kernel(const float* __restrict__ x, int S, int chunk, int bps,
                               const int* __restrict__ blockBase,
                               float4* __restrict__ A, int* __restrict__ iA, int CAP) {
    __shared__ int s_cnt;
    __shared__ int s_base;
    int b = blockIdx.x;
    int s = b / bps, c = b % bps;
    if (threadIdx.x == 0) {
        s_cnt = 0;
        s_base = blockBase[b] - blockBase[s * bps];  // segment-relative
    }
    __syncthreads();
    int start = s * S + c * chunk;
    int end = min(start + chunk, s * S + S);
    for (int i = start + threadIdx.x; i < end; i += blockDim.x) {
        float beta = x[(size_t)i * 17 + 9];
        if (beta >= 0.85f) {
            int p = atomicAdd(&s_cnt, 1);
            int pos = s_base + p;
            if (pos < CAP) {
                A[(size_t)s * CAP + pos] = make_float4(x[(size_t)i * 17 + 14],
                                                       x[(size_t)i * 17 + 15],
                                                       x[(size_t)i * 17 + 16], beta);
                iA[(size_t)s * CAP + pos] = i;
            }
        }
    }
}

// One block (1024 threads) per segment. Each pass: drop entries within T_D of
// the current center, compact survivors into the other buffer, and compute the
// max-(beta, lowest idx) survivor = next pick. Pass 0 uses a far-away fake
// center so it is a pure copy+argmax.
__launch_bounds__(1024)
__global__ void greedy_kernel(float4* __restrict__ A, int* __restrict__ iA,
                              float4* __restrict__ Bb, int* __restrict__ iB,
                              const int* __restrict__ candCount, int CAP,
                              int* __restrict__ condList, int* __restrict__ condCount,
                              int CCAP) {
    const int s = blockIdx.x;
    const int tid = threadIdx.x;
    const int lane = tid & 63;
    const int wid = tid >> 6;

    __shared__ u64 wkey[16];
    __shared__ float wcx[16], wcy[16], wcz[16];
    __shared__ int s_newN;
    __shared__ float s_ctr[3];
    __shared__ u64 s_bestkey;

    float4* cur = A + (size_t)s * CAP;
    int*    icur = iA + (size_t)s * CAP;
    float4* nxt = Bb + (size_t)s * CAP;
    int*    inxt = iB + (size_t)s * CAP;
    int n = candCount[s];
    if (n > CAP) n = CAP;
    int* clist = condList + (size_t)s * CCAP;

    float ctrx = 1e30f, ctry = 1e30f, ctrz = 1e30f;
    int cnt = 0;

    while (true) {
        if (tid == 0) s_newN = 0;
        __syncthreads();

        u64 bkey = 0; float bcx = 0.f, bcy = 0.f, bcz = 0.f;
        for (int j = tid; j < n; j += 1024) {
            float4 c = cur[j];
            int gi = icur[j];
            // match numpy/jax f32 semantics exactly: no FMA contraction,
            // ((dx^2 + dy^2) + dz^2) < f32(0.09)
            float dx = __fsub_rn(c.x, ctrx);
            float dy = __fsub_rn(c.y, ctry);
            float dz = __fsub_rn(c.z, ctrz);
            float dsq = __fadd_rn(__fadd_rn(__fmul_rn(dx, dx), __fmul_rn(dy, dy)),
                                  __fmul_rn(dz, dz));
            bool survive = !(dsq < 0.09f);
            u64 smask = __ballot(survive);
            if (survive) {
                u32 bb = __float_as_uint(c.w);  // beta in [0.85,1): bits monotone
                u64 key = ((u64)bb << 32) | (u64)(0xFFFFFFFFu - (u32)gi); // ties -> lowest idx
                if (key > bkey) { bkey = key; bcx = c.x; bcy = c.y; bcz = c.z; }
                int leader = __ffsll((unsigned long long)smask) - 1;
                int base = 0;
                if (lane == leader) base = atomicAdd(&s_newN, __popcll(smask));
                base = __shfl(base, leader);
                int off = __popcll(smask & ((1ull << lane) - 1ull));
                nxt[base + off] = c;
                inxt[base + off] = gi;
            }
        }

        // wave-level max reduce carrying the winner's coords
        for (int off = 32; off > 0; off >>= 1) {
            u64 ok = __shfl_down(bkey, off);
            float ox = __shfl_down(bcx, off);
            float oy = __shfl_down(bcy, off);
            float oz = __shfl_down(bcz, off);
            if (ok > bkey) { bkey = ok; bcx = ox; bcy = oy; bcz = oz; }
        }
        if (lane == 0) { wkey[wid] = bkey; wcx[wid] = bcx; wcy[wid] = bcy; wcz[wid] = bcz; }
        __syncthreads();
        if (wid == 0) {
            u64 k2 = (lane < 16) ? wkey[lane] : 0;
            float x2 = (lane < 16) ? wcx[lane] : 0.f;
            float y2 = (lane < 16) ? wcy[lane] : 0.f;
            float z2 = (lane < 16) ? wcz[lane] : 0.f;
            for (int off = 8; off > 0; off >>= 1) {
                u64 ok = __shfl_down(k2, off);
                float ox = __shfl_down(x2, off);
                float oy = __shfl_down(y2, off);
                float oz = __shfl_down(z2, off);
                if (ok > k2) { k2 = ok; x2 = ox; y2 = oy; z2 = oz; }
            }
            if (lane == 0) { s_bestkey = k2; s_ctr[0] = x2; s_ctr[1] = y2; s_ctr[2] = z2; }
        }
        __syncthreads();

        int newN = s_newN;
        if (newN == 0 || s_bestkey == 0) break;

        if (tid == 0 && cnt < CCAP)
            clist[cnt] = (int)(0xFFFFFFFFu - (u32)(s_bestkey & 0xFFFFFFFFull));
        cnt++;
        ctrx = s_ctr[0]; ctry = s_ctr[1]; ctrz = s_ctr[2];

        float4* t4 = cur; cur = nxt; nxt = t4;
        int* ti = icur; icur = inxt; inxt = ti;
        n = newN;
        __syncthreads();  // writers of nxt done before anyone re-reads as cur
    }
    if (tid == 0) condCount[s] = cnt;
}

// Rank-sort each segment's pick list ascending (lists are tiny, ~40 entries),
// place into global sorted order (segment-major = globally ascending), and
// write ncond (cumulative counts) as float32.
__global__ void finalize_kernel(const int* __restrict__ condList,
                                const int* __restrict__ condCount, int CCAP,
                                int* __restrict__ sorted, int* __restrict__ prefix,
                                float* __restrict__ ncond_out, int nseg, int rows) {
    __shared__ int lst[2048];
    __shared__ int pfx[9];
    int tid = threadIdx.x;
    if (tid == 0) {
        int acc = 0; pfx[0] = 0;
        for (int s2 = 0; s2 < nseg; s2++) { acc += condCount[s2]; pfx[s2 + 1] = acc; }
    }
    __syncthreads();
    if (tid <= nseg) { prefix[tid] = pfx[tid]; ncond_out[tid] = (float)pfx[tid]; }
    for (int s2 = 0; s2 < nseg; s2++) {
        int ns = condCount[s2]; if (ns > CCAP) ns = CCAP;
        for (int i = tid; i < ns; i += blockDim.x) lst[i] = condList[(size_t)s2 * CCAP + i];
        __syncthreads();
        for (int i = tid; i < ns; i += blockDim.x) {
            int v = lst[i]; int rank = 0;
            for (int j = 0; j < ns; j++) rank += (lst[j] < v);
            int pos = pfx[s2] + rank;
            if (pos < rows) sorted[pos] = v;
        }
        __syncthreads();
    }
}

__global__ void emit_kernel(const float* __restrict__ x, const int* __restrict__ sorted,
                            const int* __restrict__ prefix, float* __restrict__ out,
                            int rows, int nseg) {
    int e = blockIdx.x * blockDim.x + threadIdx.x;
    if (e >= rows * 17) return;
    int total = prefix[nseg];
    int j = e / 17, k = e - j * 17;
    float v = 0.f;
    if (j < total) v = x[(size_t)sorted[j] * 17 + k];
    out[e] = v;
}

extern "C" void kernel_launch(void* const* d_in, const int* in_sizes, int n_in,
                              void* d_out, int out_size, void* d_ws, size_t ws_size,
                              hipStream_t stream) {
    const float* x = (const float*)d_in[0];
    const int nseg = in_sizes[1] - 1;          // 4
    const int N = in_sizes[0] / 17;            // 1,000,000
    const int S = N / nseg;                    // 250,000
    const int rows = (out_size - (nseg + 1)) / 17;  // 1024 (MAX_COND)
    const int CCAP = 2048;

    const int bps = 1024 / nseg;               // blocks per segment (256)
    const int nBlocks = nseg * bps;            // 1024 (fits one scan block)
    const int chunk = (S + bps - 1) / bps;

    // workspace: [A][B] float4, [iA][iB], condList, condCount, candCount,
    // sorted, prefix, blockCount, blockBase
    char* w = (char*)d_ws;
    size_t fixedBytes = (size_t)nseg * CCAP * 4 + (size_t)nseg * 4 * 2 +
                        (size_t)rows * 4 + (size_t)(nseg + 1) * 4 +
                        (size_t)nBlocks * 4 * 2 + 4096;
    size_t perCand = (size_t)nseg * 2 * (16 + 4);
    size_t avail = (ws_size > fixedBytes) ? (ws_size - fixedBytes) : 0;
    int CAP = (int)(avail / perCand);
    if (CAP > 65536) CAP = 65536;   // ~1.75x the expected 37.5k candidates/segment
    if (CAP < 1) CAP = 1;

    float4* A  = (float4*)w;
    float4* Bb = A + (size_t)nseg * CAP;
    int* iA = (int*)(Bb + (size_t)nseg * CAP);
    int* iB = iA + (size_t)nseg * CAP;
    int* condList  = iB + (size_t)nseg * CAP;
    int* condCount = condList + (size_t)nseg * CCAP;
    int* candCount = condCount + nseg;
    int* sorted    = candCount + nseg;
    int* prefix    = sorted + rows;
    int* blockCount = prefix + (nseg + 1);
    int* blockBase  = blockCount + nBlocks;
    float* out = (float*)d_out;

    count_kernel<<<nBlocks, 256, 0, stream>>>(x, S, chunk, bps, blockCount);
    scan_kernel<<<1, 1024, 0, stream>>>(blockCount, nBlocks, blockBase, candCount,
                                        nseg, bps);
    scatter_kernel<<<nBlocks, 256, 0, stream>>>(x, S, chunk, bps, blockBase, A, iA, CAP);
    greedy_kernel<<<nseg, 1024, 0, stream>>>(A, iA, Bb, iB, candCount, CAP,
                                             condList, condCount, CCAP);
    finalize_kernel<<<1, 256, 0, stream>>>(condList, condCount, CCAP, sorted, prefix,
                                           out + (size_t)rows * 17, nseg, rows);
    emit_kernel<<<(rows * 17 + 255) / 256, 256, 0, stream>>>(x, sorted, prefix, out,
                                                             rows, nseg);
}